// Round 1
// baseline (441.220 us; speedup 1.0000x reference)
//
#include <hip/hip_runtime.h>

#define N_NODES 50000
#define N_EDGES 800000
#define IN_FEAT 256
#define OUT_FEAT 128
#define P_EDGE 0.2f
#define P_NODE 0.1f
#define BN_EPS 1e-5f

// ---------------- degree counting (kept edges only) ----------------
__global__ __launch_bounds__(256) void k_deg(const int* __restrict__ src,
    const int* __restrict__ dst, const float* __restrict__ er,
    unsigned* __restrict__ deg_src, unsigned* __restrict__ deg_dst) {
  int e = blockIdx.x * 256 + threadIdx.x;
  if (e < N_EDGES && er[e] >= P_EDGE) {
    atomicAdd(&deg_src[src[e]], 1u);
    atomicAdd(&deg_dst[dst[e]], 1u);
  }
}

// ---------------- allocate contiguous per-dst ranges (unsorted CSR) ----------------
__global__ __launch_bounds__(256) void k_alloc(const unsigned* __restrict__ deg_dst,
    unsigned* __restrict__ row_start, unsigned* __restrict__ cursor,
    unsigned* __restrict__ total) {
  int n = blockIdx.x * 256 + threadIdx.x;
  if (n < N_NODES) {
    unsigned c = deg_dst[n];
    unsigned r = atomicAdd(total, c);
    row_start[n] = r;
    cursor[n] = r;
  }
}

// ---------------- scatter kept edges' src into CSR slots ----------------
__global__ __launch_bounds__(256) void k_scatter(const int* __restrict__ src,
    const int* __restrict__ dst, const float* __restrict__ er,
    unsigned* __restrict__ cursor, unsigned* __restrict__ edge_src) {
  int e = blockIdx.x * 256 + threadIdx.x;
  if (e < N_EDGES && er[e] >= P_EDGE) {
    unsigned p = atomicAdd(&cursor[dst[e]], 1u);
    edge_src[p] = (unsigned)src[e];
  }
}

// ---------------- h_scaled = (feat @ W) * rsqrt(max(deg_src,1)) ----------------
// block = 256 threads: 32 col-groups (4 cols each) x 8 node-groups (8 nodes each)
// -> 64 nodes x 128 cols per block, 32 fp32 accumulators/thread.
__global__ __launch_bounds__(256) void k_gemm(const float* __restrict__ feat,
    const float* __restrict__ W, const unsigned* __restrict__ deg_src,
    float* __restrict__ h) {
  const int cg = threadIdx.x & 31;
  const int ng = threadIdx.x >> 5;
  const int n0 = blockIdx.x * 64 + ng * 8;
  const int c4 = cg * 4;
  float acc[8][4];
#pragma unroll
  for (int i = 0; i < 8; i++)
#pragma unroll
    for (int c = 0; c < 4; c++) acc[i][c] = 0.f;

  for (int k = 0; k < IN_FEAT; k += 4) {
    float4 w0 = *(const float4*)(W + (k + 0) * OUT_FEAT + c4);
    float4 w1 = *(const float4*)(W + (k + 1) * OUT_FEAT + c4);
    float4 w2 = *(const float4*)(W + (k + 2) * OUT_FEAT + c4);
    float4 w3 = *(const float4*)(W + (k + 3) * OUT_FEAT + c4);
#pragma unroll
    for (int i = 0; i < 8; i++) {
      int n = n0 + i;
      n = n < N_NODES ? n : (N_NODES - 1);  // clamp: safe duplicate read, store guarded
      float4 f = *(const float4*)(feat + (size_t)n * IN_FEAT + k);
      acc[i][0] = fmaf(f.x, w0.x, acc[i][0]); acc[i][0] = fmaf(f.y, w1.x, acc[i][0]);
      acc[i][0] = fmaf(f.z, w2.x, acc[i][0]); acc[i][0] = fmaf(f.w, w3.x, acc[i][0]);
      acc[i][1] = fmaf(f.x, w0.y, acc[i][1]); acc[i][1] = fmaf(f.y, w1.y, acc[i][1]);
      acc[i][1] = fmaf(f.z, w2.y, acc[i][1]); acc[i][1] = fmaf(f.w, w3.y, acc[i][1]);
      acc[i][2] = fmaf(f.x, w0.z, acc[i][2]); acc[i][2] = fmaf(f.y, w1.z, acc[i][2]);
      acc[i][2] = fmaf(f.z, w2.z, acc[i][2]); acc[i][2] = fmaf(f.w, w3.z, acc[i][2]);
      acc[i][3] = fmaf(f.x, w0.w, acc[i][3]); acc[i][3] = fmaf(f.y, w1.w, acc[i][3]);
      acc[i][3] = fmaf(f.z, w2.w, acc[i][3]); acc[i][3] = fmaf(f.w, w3.w, acc[i][3]);
    }
  }
#pragma unroll
  for (int i = 0; i < 8; i++) {
    int n = n0 + i;
    if (n < N_NODES) {
      unsigned d = deg_src[n];
      float s = rsqrtf((float)(d > 0u ? d : 1u));
      float4 o = make_float4(acc[i][0] * s, acc[i][1] * s, acc[i][2] * s, acc[i][3] * s);
      *(float4*)(h + (size_t)n * OUT_FEAT + c4) = o;
    }
  }
}

// ---------------- per-dst aggregation: out[d,:] = sum h[src]*rsqrt(deg_dst) + b ----------------
__global__ __launch_bounds__(128) void k_agg(const float* __restrict__ h,
    const unsigned* __restrict__ edge_src, const unsigned* __restrict__ row_start,
    const unsigned* __restrict__ deg_dst, const float* __restrict__ bias,
    float* __restrict__ out) {
  const int d = blockIdx.x;
  const int f = threadIdx.x;
  const unsigned r0 = row_start[d];
  const unsigned cnt = deg_dst[d];
  float acc = 0.f;
  unsigned i = 0;
  for (; i + 4 <= cnt; i += 4) {
    unsigned s0 = edge_src[r0 + i + 0];
    unsigned s1 = edge_src[r0 + i + 1];
    unsigned s2 = edge_src[r0 + i + 2];
    unsigned s3 = edge_src[r0 + i + 3];
    float v0 = h[(size_t)s0 * OUT_FEAT + f];
    float v1 = h[(size_t)s1 * OUT_FEAT + f];
    float v2 = h[(size_t)s2 * OUT_FEAT + f];
    float v3 = h[(size_t)s3 * OUT_FEAT + f];
    acc += (v0 + v1) + (v2 + v3);
  }
  for (; i < cnt; ++i) {
    unsigned s = edge_src[r0 + i];
    acc += h[(size_t)s * OUT_FEAT + f];
  }
  float sc = rsqrtf((float)(cnt > 0u ? cnt : 1u));
  out[(size_t)d * OUT_FEAT + f] = fmaf(acc, sc, bias[f]);
}

// ---------------- column sum / sumsq over 50000 rows ----------------
#define STAT_ROWS 512
__global__ __launch_bounds__(256) void k_stats(const float* __restrict__ out,
    float* __restrict__ col_sum, float* __restrict__ col_sumsq) {
  const int c = threadIdx.x & 127;
  const int rh = threadIdx.x >> 7;
  int r0 = blockIdx.x * STAT_ROWS;
  int r1 = r0 + STAT_ROWS; if (r1 > N_NODES) r1 = N_NODES;
  float s = 0.f, ss = 0.f;
  for (int r = r0 + rh; r < r1; r += 2) {
    float v = out[(size_t)r * OUT_FEAT + c];
    s += v;
    ss = fmaf(v, v, ss);
  }
  __shared__ float l1[256], l2[256];
  l1[threadIdx.x] = s; l2[threadIdx.x] = ss;
  __syncthreads();
  if (rh == 0) {
    atomicAdd(&col_sum[c], l1[c] + l1[c + 128]);
    atomicAdd(&col_sumsq[c], l2[c] + l2[c + 128]);
  }
}

// ---------------- finalize BN affine coefs ----------------
__global__ void k_fin(const float* __restrict__ col_sum, const float* __restrict__ col_sumsq,
    const float* __restrict__ gamma, const float* __restrict__ beta,
    float* __restrict__ a_coef, float* __restrict__ b_coef) {
  int c = threadIdx.x;
  if (c < OUT_FEAT) {
    float mean = col_sum[c] * (1.0f / N_NODES);
    float var = col_sumsq[c] * (1.0f / N_NODES) - mean * mean;
    float a = gamma[c] * rsqrtf(var + BN_EPS);
    a_coef[c] = a;
    b_coef[c] = fmaf(-mean, a, beta[c]);
  }
}

// ---------------- normalize + node dropout (in place on out) ----------------
__global__ __launch_bounds__(256) void k_norm(float* __restrict__ out,
    const float* __restrict__ node_rand, const float* __restrict__ a_coef,
    const float* __restrict__ b_coef) {
  const size_t total4 = (size_t)N_NODES * OUT_FEAT / 4;
  size_t i = (size_t)blockIdx.x * 256 + threadIdx.x;
  if (i < total4) {
    int c0 = (int)((i * 4) & 127);
    float4 v = ((const float4*)out)[i];
    float4 nr = ((const float4*)node_rand)[i];
    float4 a = *(const float4*)(a_coef + c0);
    float4 b = *(const float4*)(b_coef + c0);
    const float inv = 1.0f / (1.0f - P_NODE);
    float4 o;
    o.x = (nr.x >= P_NODE ? inv : 0.f) * fmaf(v.x, a.x, b.x);
    o.y = (nr.y >= P_NODE ? inv : 0.f) * fmaf(v.y, a.y, b.y);
    o.z = (nr.z >= P_NODE ? inv : 0.f) * fmaf(v.z, a.z, b.z);
    o.w = (nr.w >= P_NODE ? inv : 0.f) * fmaf(v.w, a.w, b.w);
    ((float4*)out)[i] = o;
  }
}

extern "C" void kernel_launch(void* const* d_in, const int* in_sizes, int n_in,
                              void* d_out, int out_size, void* d_ws, size_t ws_size,
                              hipStream_t stream) {
  const float* feat  = (const float*)d_in[0];
  const float* W     = (const float*)d_in[1];
  const float* bias  = (const float*)d_in[2];
  const float* gamma = (const float*)d_in[3];
  const float* beta  = (const float*)d_in[4];
  const int*   src   = (const int*)d_in[5];
  const int*   dst   = (const int*)d_in[6];
  const float* er    = (const float*)d_in[7];
  const float* nr    = (const float*)d_in[8];
  float* out = (float*)d_out;

  char* ws = (char*)d_ws;
  // workspace layout (all offsets 16B-aligned)
  float*    h         = (float*)   (ws + 0);          // 25,600,000 B
  unsigned* edge_src  = (unsigned*)(ws + 25600000);   //  3,200,000 B
  unsigned* deg_src   = (unsigned*)(ws + 28800000);   //    200,000 B  [zeroed]
  unsigned* deg_dst   = (unsigned*)(ws + 29000000);   //    200,000 B  [zeroed]
  unsigned* total     = (unsigned*)(ws + 29200000);   //         16 B  [zeroed]
  float*    col_sum   = (float*)   (ws + 29200016);   //        512 B  [zeroed]
  float*    col_sumsq = (float*)   (ws + 29200528);   //        512 B  [zeroed]
  unsigned* row_start = (unsigned*)(ws + 29201040);   //    200,000 B
  unsigned* cursor    = (unsigned*)(ws + 29401040);   //    200,000 B
  float*    a_coef    = (float*)   (ws + 29601040);   //        512 B
  float*    b_coef    = (float*)   (ws + 29601552);   //        512 B

  hipMemsetAsync(ws + 28800000, 0, 401040, stream);

  k_deg<<<(N_EDGES + 255) / 256, 256, 0, stream>>>(src, dst, er, deg_src, deg_dst);
  k_alloc<<<(N_NODES + 255) / 256, 256, 0, stream>>>(deg_dst, row_start, cursor, total);
  k_scatter<<<(N_EDGES + 255) / 256, 256, 0, stream>>>(src, dst, er, cursor, edge_src);
  k_gemm<<<(N_NODES + 63) / 64, 256, 0, stream>>>(feat, W, deg_src, h);
  k_agg<<<N_NODES, 128, 0, stream>>>(h, edge_src, row_start, deg_dst, bias, out);
  k_stats<<<(N_NODES + STAT_ROWS - 1) / STAT_ROWS, 256, 0, stream>>>(out, col_sum, col_sumsq);
  k_fin<<<1, 128, 0, stream>>>(col_sum, col_sumsq, gamma, beta, a_coef, b_coef);
  k_norm<<<(N_NODES * OUT_FEAT / 4 + 255) / 256, 256, 0, stream>>>(out, nr, a_coef, b_coef);
}

// Round 2
// 372.023 us; speedup vs baseline: 1.1860x; 1.1860x over previous
//
#include <hip/hip_runtime.h>

#define N_NODES 50000
#define N_EDGES 800000
#define IN_FEAT 256
#define OUT_FEAT 128
#define P_EDGE 0.2f
#define P_NODE 0.1f
#define BN_EPS 1e-5f

typedef __bf16 bf16x8 __attribute__((ext_vector_type(8)));
typedef float floatx4 __attribute__((ext_vector_type(4)));

// ---------------- degree counting (kept edges only) ----------------
__global__ __launch_bounds__(256) void k_deg(const int* __restrict__ src,
    const int* __restrict__ dst, const float* __restrict__ er,
    unsigned* __restrict__ deg_src, unsigned* __restrict__ deg_dst) {
  int e = blockIdx.x * 256 + threadIdx.x;
  if (e < N_EDGES && er[e] >= P_EDGE) {
    atomicAdd(&deg_src[src[e]], 1u);
    atomicAdd(&deg_dst[dst[e]], 1u);
  }
}

// ---------------- allocate contiguous per-dst ranges (unsorted CSR) ----------------
__global__ __launch_bounds__(256) void k_alloc(const unsigned* __restrict__ deg_dst,
    unsigned* __restrict__ row_start, unsigned* __restrict__ cursor,
    unsigned* __restrict__ total) {
  int n = blockIdx.x * 256 + threadIdx.x;
  if (n < N_NODES) {
    unsigned c = deg_dst[n];
    unsigned r = atomicAdd(total, c);
    row_start[n] = r;
    cursor[n] = r;
  }
}

// ---------------- scatter kept edges' src into CSR slots ----------------
__global__ __launch_bounds__(256) void k_scatter(const int* __restrict__ src,
    const int* __restrict__ dst, const float* __restrict__ er,
    unsigned* __restrict__ cursor, unsigned* __restrict__ edge_src) {
  int e = blockIdx.x * 256 + threadIdx.x;
  if (e < N_EDGES && er[e] >= P_EDGE) {
    unsigned p = atomicAdd(&cursor[dst[e]], 1u);
    edge_src[p] = (unsigned)src[e];
  }
}

// ---------------- W (K x N fp32) -> Wt (N x K bf16) ----------------
__global__ __launch_bounds__(256) void k_prep_w(const float* __restrict__ W,
    __bf16* __restrict__ Wt) {
  int idx = blockIdx.x * 256 + threadIdx.x;  // 32768 total
  int k = idx >> 7, n = idx & 127;
  Wt[n * IN_FEAT + k] = (__bf16)W[idx];
}

__device__ inline bf16x8 cvt8(float4 a, float4 b) {
  bf16x8 v;
  v[0] = (__bf16)a.x; v[1] = (__bf16)a.y; v[2] = (__bf16)a.z; v[3] = (__bf16)a.w;
  v[4] = (__bf16)b.x; v[5] = (__bf16)b.y; v[6] = (__bf16)b.z; v[7] = (__bf16)b.w;
  return v;
}

// ---------------- h = bf16( (feat @ W) * rsqrt(max(deg_src,1)) ) via MFMA ----------------
// 256 threads = 4 waves; wave w: rows m0+16w .. +15, all 128 cols.
// A frag: A[m=lane&15][k=quad*8+j]  (fp32 load + in-register bf16 convert)
// B frag: B[n=lane&15][k=quad*8+j]  from Wt (N x K bf16)
// C/D:    col=lane&15, row=quad*4+reg
__global__ __launch_bounds__(256) void k_gemm(const float* __restrict__ feat,
    const __bf16* __restrict__ Wt, const unsigned* __restrict__ deg_src,
    __bf16* __restrict__ h) {
  const int lane = threadIdx.x & 63;
  const int wave = threadIdx.x >> 6;
  const int l16 = lane & 15;
  const int quad = lane >> 4;
  const int m0 = blockIdx.x * 64 + wave * 16;

  int mload = m0 + l16;
  if (mload >= N_NODES) mload = N_NODES - 1;  // clamp load row; stores guarded

  // load + convert the full A row-slice: 8 frags of 8 bf16 (32 VGPRs)
  bf16x8 a[8];
#pragma unroll
  for (int kk = 0; kk < 8; kk++) {
    const float4* p = (const float4*)(feat + (size_t)mload * IN_FEAT + kk * 32 + quad * 8);
    float4 f0 = p[0];
    float4 f1 = p[1];
    a[kk] = cvt8(f0, f1);
  }

  floatx4 acc[8];
#pragma unroll
  for (int g = 0; g < 8; g++) {
    const __bf16* wrow = Wt + (size_t)(g * 16 + l16) * IN_FEAT + quad * 8;
    floatx4 c = {0.f, 0.f, 0.f, 0.f};
#pragma unroll
    for (int kk = 0; kk < 8; kk++) {
      bf16x8 b = *(const bf16x8*)(wrow + kk * 32);
      c = __builtin_amdgcn_mfma_f32_16x16x32_bf16(a[kk], b, c, 0, 0, 0);
    }
    acc[g] = c;
  }

  // epilogue: lane holds rows m0+quad*4+r, col g*16+l16
  const int rbase = m0 + quad * 4;
  float s[4];
#pragma unroll
  for (int r = 0; r < 4; r++) {
    int row = rbase + r;
    unsigned d = (row < N_NODES) ? deg_src[row] : 1u;
    s[r] = rsqrtf((float)(d > 0u ? d : 1u));
  }
#pragma unroll
  for (int g = 0; g < 8; g++) {
#pragma unroll
    for (int r = 0; r < 4; r++) {
      int row = rbase + r;
      if (row < N_NODES)
        h[(size_t)row * OUT_FEAT + g * 16 + l16] = (__bf16)(acc[g][r] * s[r]);
    }
  }
}

// ---------------- per-dst aggregation: out[d,:] = sum h[src]*rsqrt(deg_dst) + b ----------------
__global__ __launch_bounds__(128) void k_agg(const __bf16* __restrict__ h,
    const unsigned* __restrict__ edge_src, const unsigned* __restrict__ row_start,
    const unsigned* __restrict__ deg_dst, const float* __restrict__ bias,
    float* __restrict__ out) {
  const int d = blockIdx.x;
  const int f = threadIdx.x;
  const unsigned r0 = row_start[d];
  const unsigned cnt = deg_dst[d];
  float acc = 0.f;
  unsigned i = 0;
  for (; i + 4 <= cnt; i += 4) {
    unsigned s0 = edge_src[r0 + i + 0];
    unsigned s1 = edge_src[r0 + i + 1];
    unsigned s2 = edge_src[r0 + i + 2];
    unsigned s3 = edge_src[r0 + i + 3];
    float v0 = (float)h[(size_t)s0 * OUT_FEAT + f];
    float v1 = (float)h[(size_t)s1 * OUT_FEAT + f];
    float v2 = (float)h[(size_t)s2 * OUT_FEAT + f];
    float v3 = (float)h[(size_t)s3 * OUT_FEAT + f];
    acc += (v0 + v1) + (v2 + v3);
  }
  for (; i < cnt; ++i) {
    unsigned s = edge_src[r0 + i];
    acc += (float)h[(size_t)s * OUT_FEAT + f];
  }
  float sc = rsqrtf((float)(cnt > 0u ? cnt : 1u));
  out[(size_t)d * OUT_FEAT + f] = fmaf(acc, sc, bias[f]);
}

// ---------------- column sum / sumsq over 50000 rows ----------------
#define STAT_ROWS 512
__global__ __launch_bounds__(256) void k_stats(const float* __restrict__ out,
    float* __restrict__ col_sum, float* __restrict__ col_sumsq) {
  const int c = threadIdx.x & 127;
  const int rh = threadIdx.x >> 7;
  int r0 = blockIdx.x * STAT_ROWS;
  int r1 = r0 + STAT_ROWS; if (r1 > N_NODES) r1 = N_NODES;
  float s = 0.f, ss = 0.f;
  for (int r = r0 + rh; r < r1; r += 2) {
    float v = out[(size_t)r * OUT_FEAT + c];
    s += v;
    ss = fmaf(v, v, ss);
  }
  __shared__ float l1[256], l2[256];
  l1[threadIdx.x] = s; l2[threadIdx.x] = ss;
  __syncthreads();
  if (rh == 0) {
    atomicAdd(&col_sum[c], l1[c] + l1[c + 128]);
    atomicAdd(&col_sumsq[c], l2[c] + l2[c + 128]);
  }
}

// ---------------- finalize BN affine coefs ----------------
__global__ void k_fin(const float* __restrict__ col_sum, const float* __restrict__ col_sumsq,
    const float* __restrict__ gamma, const float* __restrict__ beta,
    float* __restrict__ a_coef, float* __restrict__ b_coef) {
  int c = threadIdx.x;
  if (c < OUT_FEAT) {
    float mean = col_sum[c] * (1.0f / N_NODES);
    float var = col_sumsq[c] * (1.0f / N_NODES) - mean * mean;
    float a = gamma[c] * rsqrtf(var + BN_EPS);
    a_coef[c] = a;
    b_coef[c] = fmaf(-mean, a, beta[c]);
  }
}

// ---------------- normalize + node dropout (in place on out) ----------------
__global__ __launch_bounds__(256) void k_norm(float* __restrict__ out,
    const float* __restrict__ node_rand, const float* __restrict__ a_coef,
    const float* __restrict__ b_coef) {
  const size_t total4 = (size_t)N_NODES * OUT_FEAT / 4;
  size_t i = (size_t)blockIdx.x * 256 + threadIdx.x;
  if (i < total4) {
    int c0 = (int)((i * 4) & 127);
    float4 v = ((const float4*)out)[i];
    float4 nr = ((const float4*)node_rand)[i];
    float4 a = *(const float4*)(a_coef + c0);
    float4 b = *(const float4*)(b_coef + c0);
    const float inv = 1.0f / (1.0f - P_NODE);
    float4 o;
    o.x = (nr.x >= P_NODE ? inv : 0.f) * fmaf(v.x, a.x, b.x);
    o.y = (nr.y >= P_NODE ? inv : 0.f) * fmaf(v.y, a.y, b.y);
    o.z = (nr.z >= P_NODE ? inv : 0.f) * fmaf(v.z, a.z, b.z);
    o.w = (nr.w >= P_NODE ? inv : 0.f) * fmaf(v.w, a.w, b.w);
    ((float4*)out)[i] = o;
  }
}

extern "C" void kernel_launch(void* const* d_in, const int* in_sizes, int n_in,
                              void* d_out, int out_size, void* d_ws, size_t ws_size,
                              hipStream_t stream) {
  const float* feat  = (const float*)d_in[0];
  const float* W     = (const float*)d_in[1];
  const float* bias  = (const float*)d_in[2];
  const float* gamma = (const float*)d_in[3];
  const float* beta  = (const float*)d_in[4];
  const int*   src   = (const int*)d_in[5];
  const int*   dst   = (const int*)d_in[6];
  const float* er    = (const float*)d_in[7];
  const float* nr    = (const float*)d_in[8];
  float* out = (float*)d_out;

  char* ws = (char*)d_ws;
  // workspace layout (16B-aligned offsets)
  __bf16*   h         = (__bf16*)  (ws + 0);          // 12,800,000 B
  unsigned* edge_src  = (unsigned*)(ws + 12800000);   //  3,200,000 B
  __bf16*   Wt        = (__bf16*)  (ws + 16000000);   //     65,536 B
  unsigned* deg_src   = (unsigned*)(ws + 16065536);   //    200,000 B  [zeroed]
  unsigned* deg_dst   = (unsigned*)(ws + 16265536);   //    200,000 B  [zeroed]
  unsigned* total     = (unsigned*)(ws + 16465536);   //         16 B  [zeroed]
  float*    col_sum   = (float*)   (ws + 16465552);   //        512 B  [zeroed]
  float*    col_sumsq = (float*)   (ws + 16466064);   //        512 B  [zeroed]
  unsigned* row_start = (unsigned*)(ws + 16466576);   //    200,000 B
  unsigned* cursor    = (unsigned*)(ws + 16666576);   //    200,000 B
  float*    a_coef    = (float*)   (ws + 16866576);   //        512 B
  float*    b_coef    = (float*)   (ws + 16867088);   //        512 B

  hipMemsetAsync(ws + 16065536, 0, 401040, stream);

  k_deg<<<(N_EDGES + 255) / 256, 256, 0, stream>>>(src, dst, er, deg_src, deg_dst);
  k_alloc<<<(N_NODES + 255) / 256, 256, 0, stream>>>(deg_dst, row_start, cursor, total);
  k_scatter<<<(N_EDGES + 255) / 256, 256, 0, stream>>>(src, dst, er, cursor, edge_src);
  k_prep_w<<<(IN_FEAT * OUT_FEAT) / 256, 256, 0, stream>>>(W, Wt);
  k_gemm<<<(N_NODES + 63) / 64, 256, 0, stream>>>(feat, Wt, deg_src, h);
  k_agg<<<N_NODES, 128, 0, stream>>>(h, edge_src, row_start, deg_dst, bias, out);
  k_stats<<<(N_NODES + STAT_ROWS - 1) / STAT_ROWS, 256, 0, stream>>>(out, col_sum, col_sumsq);
  k_fin<<<1, 128, 0, stream>>>(col_sum, col_sumsq, gamma, beta, a_coef, b_coef);
  k_norm<<<(N_NODES * OUT_FEAT / 4 + 255) / 256, 256, 0, stream>>>(out, nr, a_coef, b_coef);
}